// Round 4
// baseline (353.204 us; speedup 1.0000x reference)
//
#include <hip/hip_runtime.h>
#include <hip/hip_bf16.h>
#include <cstdint>

typedef unsigned short u16;
typedef unsigned int u32;
typedef __bf16 bf16x8 __attribute__((ext_vector_type(8)));
typedef float f32x4 __attribute__((ext_vector_type(4)));

#define BDIM 2
#define TDIM 2048
#define HIDDIM 2048
#define NHEAD 16
#define NKVH 4
#define HD 128
#define MROWS (BDIM*TDIM)     /* 4096 */
#define NQKV 3072
#define KDIM 2048

#define MFMA16(a,b,c) __builtin_amdgcn_mfma_f32_16x16x32_bf16((a),(b),(c),0,0,0)

__device__ __forceinline__ u16 f2bf(float f) {
    __bf16 h = (__bf16)f;
    return __builtin_bit_cast(u16, h);
}
__device__ __forceinline__ float bf2f(u32 u) {
    u <<= 16;
    return __builtin_bit_cast(float, u);
}
__device__ __forceinline__ void gld16(const void* g, void* l) {
    __builtin_amdgcn_global_load_lds(
        (const __attribute__((address_space(1))) u32*)g,
        (__attribute__((address_space(3))) u32*)l, 16, 0, 0);
}

// DPP cross-lane (VALU pipe, not LDS): rotate within 16-lane rows.
template<int CTRL>
__device__ __forceinline__ float dpp_rot(float x) {
    return __builtin_bit_cast(float,
        __builtin_amdgcn_update_dpp(0, __builtin_bit_cast(int, x),
                                    CTRL, 0xf, 0xf, true));
}
__device__ __forceinline__ float rowmax16(float x) {
    x = fmaxf(x, dpp_rot<0x121>(x));   // row_ror:1
    x = fmaxf(x, dpp_rot<0x122>(x));   // row_ror:2
    x = fmaxf(x, dpp_rot<0x124>(x));   // row_ror:4
    x = fmaxf(x, dpp_rot<0x128>(x));   // row_ror:8
    return x;
}
__device__ __forceinline__ float rowsum16(float x) {
    x += dpp_rot<0x121>(x);
    x += dpp_rot<0x122>(x);
    x += dpp_rot<0x124>(x);
    x += dpp_rot<0x128>(x);
    return x;
}

// ---------------- fp32 -> bf16 convert (x) ----------------
__global__ __launch_bounds__(256) void cvt_x_kernel(const float* __restrict__ x,
                                                    u16* __restrict__ o) {
    size_t i = ((size_t)blockIdx.x * 256 + threadIdx.x) * 8;
    float4 a = *(const float4*)(x + i);
    float4 b = *(const float4*)(x + i + 4);
    uint4 v;
    v.x = (u32)f2bf(a.x) | ((u32)f2bf(a.y) << 16);
    v.y = (u32)f2bf(a.z) | ((u32)f2bf(a.w) << 16);
    v.z = (u32)f2bf(b.x) | ((u32)f2bf(b.y) << 16);
    v.w = (u32)f2bf(b.z) | ((u32)f2bf(b.w) << 16);
    *(uint4*)(o + i) = v;
}

// ---------------- W [K][N] fp32 -> Wt [N][K] bf16 ----------------
__global__ __launch_bounds__(256) void transpose_cvt(const float* __restrict__ src,
                                                     u16* __restrict__ dst, int N) {
    __shared__ float tile[32][33];
    int tx = threadIdx.x, ty = threadIdx.y;
    int n0 = blockIdx.x * 32, k0 = blockIdx.y * 32;
#pragma unroll
    for (int r = 0; r < 4; r++)
        tile[ty + 8*r][tx] = src[(size_t)(k0 + ty + 8*r) * N + n0 + tx];
    __syncthreads();
#pragma unroll
    for (int r = 0; r < 4; r++)
        dst[(size_t)(n0 + ty + 8*r) * KDIM + k0 + tx] = f2bf(tile[tx][ty + 8*r]);
}

// ---------------- GEMM: C[m][n] = sum_k A[m][k] * Bt[n][k] ----------------
template<int OUT_BF16>
__global__ void __launch_bounds__(256, 2) gemm_bt(const u16* __restrict__ A,
                                                  const u16* __restrict__ Bt,
                                                  void* __restrict__ C, int ldc) {
    __shared__ __align__(16) u16 Al[128 * 32];
    __shared__ __align__(16) u16 Bl[128 * 32];
    const int tid = threadIdx.x;
    const int lane = tid & 63;
    const int w = tid >> 6;
    const int wm = (w & 1) * 64;
    const int wn = (w >> 1) * 64;
    const int quad = lane >> 4;
    const int l15 = lane & 15;
    const size_t bm = (size_t)blockIdx.x * 128;
    const size_t bn = (size_t)blockIdx.y * 128;

    const int srow = lane >> 2;
    const int kq = (lane & 3) ^ ((lane >> 3) & 3);
    const int i0 = 2 * w, i1 = 2 * w + 1;

    const u16* ga0 = A + (bm + i0*16 + srow) * KDIM + kq * 8;
    const u16* ga1 = A + (bm + i1*16 + srow) * KDIM + kq * 8;
    const u16* gb0 = Bt + (bn + i0*16 + srow) * KDIM + kq * 8;
    const u16* gb1 = Bt + (bn + i1*16 + srow) * KDIM + kq * 8;

    const int swz = ((quad ^ ((l15 >> 1) & 3)) << 3);
    int aoff[4], boff[4];
#pragma unroll
    for (int t = 0; t < 4; t++) {
        aoff[t] = (wm + t*16 + l15) * 32 + swz;
        boff[t] = (wn + t*16 + l15) * 32 + swz;
    }

    f32x4 acc[4][4] = {};

    for (int kt = 0; kt < KDIM / 32; kt++) {
        gld16(ga0 + kt*32, &Al[i0 * 512]);
        gld16(ga1 + kt*32, &Al[i1 * 512]);
        gld16(gb0 + kt*32, &Bl[i0 * 512]);
        gld16(gb1 + kt*32, &Bl[i1 * 512]);
        __syncthreads();
        bf16x8 af[4], bfv[4];
#pragma unroll
        for (int t = 0; t < 4; t++) {
            af[t]  = *(const bf16x8*)&Al[aoff[t]];
            bfv[t] = *(const bf16x8*)&Bl[boff[t]];
        }
#pragma unroll
        for (int mt = 0; mt < 4; mt++)
#pragma unroll
            for (int nt = 0; nt < 4; nt++)
                acc[mt][nt] = MFMA16(af[mt], bfv[nt], acc[mt][nt]);
        __syncthreads();
    }

#pragma unroll
    for (int mt = 0; mt < 4; mt++) {
        size_t m0 = bm + wm + mt*16 + quad*4;
#pragma unroll
        for (int nt = 0; nt < 4; nt++) {
            size_t n = bn + wn + nt*16 + l15;
#pragma unroll
            for (int r = 0; r < 4; r++) {
                if (OUT_BF16)
                    ((u16*)C)[(m0 + r) * (size_t)ldc + n] = f2bf(acc[mt][nt][r]);
                else
                    ((float*)C)[(m0 + r) * (size_t)ldc + n] = acc[mt][nt][r];
            }
        }
    }
}

// ---------------- rotary (in-place on Q and K parts of QKV), Q gets scale folded ----------------
__global__ __launch_bounds__(256) void rotary_kernel(u16* __restrict__ QKV,
                                                     const float* __restrict__ cosT,
                                                     const float* __restrict__ sinT) {
    int i = blockIdx.x * 256 + threadIdx.x;   // < 4096*320
    int m = i / 320;
    int rem = i - m * 320;
    int head = rem >> 4;
    int d0 = (rem & 15) << 2;                 // 0..60
    int t = m & (TDIM - 1);
    int col;
    float sc;
    if (head < NHEAD) {
        col = head * HD + d0;
        sc = 0.08838834764831845f * 1.4426950408889634f; // 1/sqrt(128) * log2(e)
    } else {
        col = HIDDIM + (head - NHEAD) * HD + d0;
        sc = 1.0f;
    }
    u16* p0 = QKV + (size_t)m * NQKV + col;
    u16* p1 = p0 + 64;
    float4 cv = *(const float4*)(cosT + t * HD + d0);
    float4 sv = *(const float4*)(sinT + t * HD + d0);
    uint2 qa = *(const uint2*)p0;
    uint2 qb = *(const uint2*)p1;
    float f0[4] = { bf2f(qa.x & 0xffffu), bf2f(qa.x >> 16), bf2f(qa.y & 0xffffu), bf2f(qa.y >> 16) };
    float f1[4] = { bf2f(qb.x & 0xffffu), bf2f(qb.x >> 16), bf2f(qb.y & 0xffffu), bf2f(qb.y >> 16) };
    float c[4] = { cv.x, cv.y, cv.z, cv.w };
    float s[4] = { sv.x, sv.y, sv.z, sv.w };
    u16 o0[4], o1[4];
#pragma unroll
    for (int k = 0; k < 4; k++) {
        o0[k] = f2bf((f0[k] * c[k] - f1[k] * s[k]) * sc);
        o1[k] = f2bf((f1[k] * c[k] + f0[k] * s[k]) * sc);
    }
    uint2 w0, w1;
    w0.x = (u32)o0[0] | ((u32)o0[1] << 16);
    w0.y = (u32)o0[2] | ((u32)o0[3] << 16);
    w1.x = (u32)o1[0] | ((u32)o1[1] << 16);
    w1.y = (u32)o1[2] | ((u32)o1[3] << 16);
    *(uint2*)p0 = w0;
    *(uint2*)p1 = w1;
}

// ---------------- flash attention, causal, GQA ----------------
// BQ=128 (4 waves x 32 Q-rows, mt=2), BKV=64. Balanced pair (a, 15-a) of
// Q-tiles -> 34 KV-iters per block; grid (8,16,2)=256 blocks = 1/CU.
// K & V prefetched to REGISTERS one iter ahead; K stored to LDS with XOR
// chunk swizzle (conflict-free), Vt uses LV=72 padded layout (conflict-free).
// Softmax reductions via DPP row_ror (VALU pipe). P private, no extra barrier.
__global__ void __launch_bounds__(256, 2) attn_kernel(const u16* __restrict__ QKV,
                                                      u16* __restrict__ AO) {
    constexpr int LV = 72;   // Vt row stride
    constexpr int LP = 72;   // P row stride
    __shared__ __align__(16) u16 Kl[64 * 128];   // K tile (chunk-swizzled)
    __shared__ __align__(16) u16 Vt[128 * LV];   // V transposed [d][s]
    __shared__ __align__(16) u16 Pl[128 * LP];   // P tile

    const int pa = blockIdx.x;   // pair index 0..7
    const int h  = blockIdx.y;
    const int b  = blockIdx.z;
    const int kh = h >> 2;
    const int tid = threadIdx.x;
    const int lane = tid & 63;
    const int w = tid >> 6;
    const int quad = lane >> 4;
    const int l15 = lane & 15;

    const size_t rowbase = (size_t)b * TDIM;
    const u16* Qb = QKV + rowbase * NQKV + h * HD;
    const u16* Kb = QKV + rowbase * NQKV + HIDDIM + kh * HD;
    const u16* Vb = Kb + NKVH * HD;

    // K staging: thread covers chunks c = tid + 256*i -> row c>>4, chunk c&15
    const int kch = tid & 15;
    int kprow[4];
#pragma unroll
    for (int i = 0; i < 4; i++) kprow[i] = (tid >> 4) + 16*i;
    // V staging lane mapping: sp (s-pair), dch (d-chunk of 8)
    const int sp0 = tid & 31, dch0 = tid >> 5, dch1 = dch0 + 8;

#pragma unroll 1
    for (int ph = 0; ph < 2; ph++) {
        const int qt = ph ? (15 - pa) : pa;   // Q-tile index, 128 rows
        const int jend = 2*qt + 1;

        // Q fragments: wave w owns rows qt*128 + w*32 + mt*16 (+l15)
        bf16x8 qf[2][4];
#pragma unroll
        for (int mt = 0; mt < 2; mt++) {
            const u16* qr = Qb + (size_t)(qt*128 + w*32 + mt*16 + l15) * NQKV;
#pragma unroll
            for (int kt = 0; kt < 4; kt++)
                qf[mt][kt] = *(const bf16x8*)(qr + kt*32 + quad*8);
        }
        f32x4 O[2][8] = {};
        float mrun[2][4], lrun[2][4];
#pragma unroll
        for (int mt = 0; mt < 2; mt++)
#pragma unroll
            for (int r = 0; r < 4; r++) { mrun[mt][r] = -1e30f; lrun[mt][r] = 0.0f; }

        // ---- prologue: prefetch K(0), V(0) into registers ----
        uint4 kr[4];
#pragma unroll
        for (int i = 0; i < 4; i++)
            kr[i] = *(const uint4*)(Kb + (size_t)kprow[i] * NQKV + kch*8);
        uint4 vr0a, vr0b, vr1a, vr1b;
        {
            const u16* g0 = Vb + (size_t)(sp0*2) * NQKV + dch0*8;
            vr0a = *(const uint4*)g0;
            vr0b = *(const uint4*)(g0 + NQKV);
            const u16* g1 = Vb + (size_t)(sp0*2) * NQKV + dch1*8;
            vr1a = *(const uint4*)g1;
            vr1b = *(const uint4*)(g1 + NQKV);
        }

#pragma unroll 1
        for (int j = 0; j <= jend; j++) {
            // ---- K regs -> LDS with chunk swizzle (ch ^ (row&7)) ----
#pragma unroll
            for (int i = 0; i < 4; i++)
                *(uint4*)&Kl[kprow[i]*128 + (kch ^ (kprow[i] & 7))*8] = kr[i];
            // ---- V regs -> Vt [d][s], LV=72 (conflict-free) ----
            {
                u32 ra[4] = { vr0a.x, vr0a.y, vr0a.z, vr0a.w };
                u32 rb[4] = { vr0b.x, vr0b.y, vr0b.z, vr0b.w };
                int s = sp0*2, d0 = dch0*8;
#pragma unroll
                for (int k2 = 0; k2 < 4; k2++) {
                    u32 lo = (ra[k2] & 0xffffu) | (rb[k2] << 16);
                    u32 hi = (ra[k2] >> 16) | (rb[k2] & 0xffff0000u);
                    *(u32*)&Vt[(d0 + 2*k2)     * LV + s] = lo;
                    *(u32*)&Vt[(d0 + 2*k2 + 1) * LV + s] = hi;
                }
                u32 rc[4] = { vr1a.x, vr1a.y, vr1a.z, vr1a.w };
                u32 rd[4] = { vr1b.x, vr1b.y, vr1b.z, vr1b.w };
                d0 = dch1*8;
#pragma unroll
                for (int k2 = 0; k2 < 4; k2++) {
                    u32 lo = (rc[k2] & 0xffffu) | (rd[k2] << 16);
                    u32 hi = (rc[k2] >> 16) | (rd[k2] & 0xffff0000u);
                    *(u32*)&Vt[(d0 + 2*k2)     * LV + s] = lo;
                    *(u32*)&Vt[(d0 + 2*k2 + 1) * LV + s] = hi;
                }
            }
            __syncthreads();   // [A] tiles visible

            // ---- prefetch K(j+1), V(j+1) into regs (hidden behind compute) ----
            if (j < jend) {
                const u16* Kbn = Kb + (size_t)(j+1) * 64 * NQKV;
#pragma unroll
                for (int i = 0; i < 4; i++)
                    kr[i] = *(const uint4*)(Kbn + (size_t)kprow[i] * NQKV + kch*8);
                const u16* Vbn = Vb + (size_t)(j+1) * 64 * NQKV;
                const u16* g0 = Vbn + (size_t)(sp0*2) * NQKV + dch0*8;
                vr0a = *(const uint4*)g0;
                vr0b = *(const uint4*)(g0 + NQKV);
                const u16* g1 = Vbn + (size_t)(sp0*2) * NQKV + dch1*8;
                vr1a = *(const uint4*)g1;
                vr1b = *(const uint4*)(g1 + NQKV);
            }

            // wave fully masked? (all its rows < first col of this KV tile)
            if (j*64 <= qt*128 + w*32 + 31) {
                // ---- S = Q K^T (Q pre-scaled by 1/sqrt(d)*log2e) ----
                f32x4 S[2][4] = {};
#pragma unroll
                for (int kt = 0; kt < 4; kt++) {
                    int p = (kt*4 + quad) ^ (l15 & 7);
#pragma unroll
                    for (int nt = 0; nt < 4; nt++) {
                        bf16x8 bfr = *(const bf16x8*)&Kl[(nt*16 + l15)*128 + p*8];
                        S[0][nt] = MFMA16(qf[0][kt], bfr, S[0][nt]);
                        S[1][nt] = MFMA16(qf[1][kt], bfr, S[1][nt]);
                    }
                }

                // ---- causal mask (only j in {2qt, 2qt+1} are boundary) ----
                if (j >= 2*qt) {
                    int tbase = qt*128 + w*32;
                    int sbase = j*64;
#pragma unroll
                    for (int mt = 0; mt < 2; mt++)
#pragma unroll
                        for (int nt = 0; nt < 4; nt++) {
                            int scol = sbase + nt*16 + l15;
#pragma unroll
                            for (int r = 0; r < 4; r++) {
                                int trow = tbase + mt*16 + quad*4 + r;
                                if (scol > trow) S[mt][nt][r] = -1e30f;
                            }
                        }
                }

                // ---- online softmax (row = 16 consecutive lanes -> DPP) ----
                float alpha[2][4];
#pragma unroll
                for (int mt = 0; mt < 2; mt++)
#pragma unroll
                    for (int r = 0; r < 4; r++) {
                        float mx = fmaxf(fmaxf(S[mt][0][r], S[mt][1][r]),
                                         fmaxf(S[mt][2][r], S[mt][3][r]));
                        mx = rowmax16(mx);
                        float mnew = fmaxf(mrun[mt][r], mx);
                        float al = __builtin_amdgcn_exp2f(mrun[mt][r] - mnew);
                        mrun[mt][r] = mnew;
                        alpha[mt][r] = al;
                        float rs = 0.0f;
#pragma unroll
                        for (int nt = 0; nt < 4; nt++) {
                            float p = __builtin_amdgcn_exp2f(S[mt][nt][r] - mnew);
                            S[mt][nt][r] = p;
                            rs += p;
                        }
                        rs = rowsum16(rs);
                        lrun[mt][r] = lrun[mt][r] * al + rs;
                    }
                bool need = false;
#pragma unroll
                for (int mt = 0; mt < 2; mt++)
#pragma unroll
                    for (int r = 0; r < 4; r++) need |= (alpha[mt][r] < 1.0f);
                if (__any(need)) {
#pragma unroll
                    for (int mt = 0; mt < 2; mt++)
#pragma unroll
                        for (int nt = 0; nt < 8; nt++)
#pragma unroll
                            for (int r = 0; r < 4; r++)
                                O[mt][nt][r] *= alpha[mt][r];
                }

                // ---- write P (own rows; no barrier needed) ----
#pragma unroll
                for (int mt = 0; mt < 2; mt++)
#pragma unroll
                    for (int nt = 0; nt < 4; nt++)
#pragma unroll
                        for (int r = 0; r < 4; r++)
                            Pl[(w*32 + mt*16 + quad*4 + r) * LP + nt*16 + l15] =
                                f2bf(S[mt][nt][r]);

                // ---- O += P V (V fragments shared across mt) ----
#pragma unroll
                for (int kt = 0; kt < 2; kt++) {
                    bf16x8 pa0 = *(const bf16x8*)&Pl[(w*32 + l15) * LP + kt*32 + quad*8];
                    bf16x8 pa1 = *(const bf16x8*)&Pl[(w*32 + 16 + l15) * LP + kt*32 + quad*8];
#pragma unroll
                    for (int nt = 0; nt < 8; nt++) {
                        bf16x8 bv = *(const bf16x8*)&Vt[(nt*16 + l15) * LV + kt*32 + quad*8];
                        O[0][nt] = MFMA16(pa0, bv, O[0][nt]);
                        O[1][nt] = MFMA16(pa1, bv, O[1][nt]);
                    }
                }
            }
            __syncthreads();   // [B] tiles free for next iter's staging
        }

        // ---- epilogue: O /= l, store bf16 ----
#pragma unroll
        for (int mt = 0; mt < 2; mt++) {
            float inv[4];
#pragma unroll
            for (int r = 0; r < 4; r++) inv[r] = 1.0f / lrun[mt][r];
            size_t row0 = rowbase + qt*128 + w*32 + mt*16 + quad*4;
#pragma unroll
            for (int nt = 0; nt < 8; nt++) {
                size_t cix = (size_t)h * HD + nt*16 + l15;
#pragma unroll
                for (int r = 0; r < 4; r++)
                    AO[(row0 + r) * HIDDIM + cix] = f2bf(O[mt][nt][r] * inv[r]);
            }
        }
    }
}

extern "C" void kernel_launch(void* const* d_in, const int* in_sizes, int n_in,
                              void* d_out, int out_size, void* d_ws, size_t ws_size,
                              hipStream_t stream) {
    (void)in_sizes; (void)n_in; (void)out_size; (void)ws_size;
    const float* x    = (const float*)d_in[0];
    const float* cosT = (const float*)d_in[1];
    const float* sinT = (const float*)d_in[2];
    const float* Wq   = (const float*)d_in[3];
    const float* Wk   = (const float*)d_in[4];
    const float* Wv   = (const float*)d_in[5];
    const float* Wo   = (const float*)d_in[6];

    char* ws = (char*)d_ws;
    u16* QKV   = (u16*)ws;                                             // 4096*3072 bf16
    u16* xb    = (u16*)(ws + (size_t)MROWS * NQKV * 2);                // 4096*2048 (then attn_out)
    u16* Wqkvt = (u16*)(ws + (size_t)MROWS * NQKV * 2 + (size_t)MROWS * HIDDIM * 2); // 3072*2048
    u16* Wot   = Wqkvt + (size_t)NQKV * KDIM;                          // 2048*2048

    cvt_x_kernel<<<4096, 256, 0, stream>>>(x, xb);
    dim3 tb(32, 8);
    transpose_cvt<<<dim3(64, 64), tb, 0, stream>>>(Wq, Wqkvt, 2048);
    transpose_cvt<<<dim3(16, 64), tb, 0, stream>>>(Wk, Wqkvt + (size_t)2048 * KDIM, 512);
    transpose_cvt<<<dim3(16, 64), tb, 0, stream>>>(Wv, Wqkvt + (size_t)2560 * KDIM, 512);
    transpose_cvt<<<dim3(64, 64), tb, 0, stream>>>(Wo, Wot, 2048);

    gemm_bt<1><<<dim3(32, 24), 256, 0, stream>>>(xb, Wqkvt, QKV, NQKV);
    rotary_kernel<<<5120, 256, 0, stream>>>(QKV, cosT, sinT);
    attn_kernel<<<dim3(8, 16, 2), 256, 0, stream>>>(QKV, xb);
    gemm_bt<0><<<dim3(32, 16), 256, 0, stream>>>(xb, Wot, d_out, HIDDIM);
}

// Round 5
// 309.343 us; speedup vs baseline: 1.1418x; 1.1418x over previous
//
#include <hip/hip_runtime.h>
#include <hip/hip_bf16.h>
#include <cstdint>

typedef unsigned short u16;
typedef unsigned int u32;
typedef __bf16 bf16x8 __attribute__((ext_vector_type(8)));
typedef float f32x4 __attribute__((ext_vector_type(4)));

#define BDIM 2
#define TDIM 2048
#define HIDDIM 2048
#define NHEAD 16
#define NKVH 4
#define HD 128
#define MROWS (BDIM*TDIM)     /* 4096 */
#define NQKV 3072
#define KDIM 2048

#define MFMA16(a,b,c) __builtin_amdgcn_mfma_f32_16x16x32_bf16((a),(b),(c),0,0,0)

__device__ __forceinline__ u16 f2bf(float f) {
    __bf16 h = (__bf16)f;
    return __builtin_bit_cast(u16, h);
}
__device__ __forceinline__ float bf2f(u32 u) {
    u <<= 16;
    return __builtin_bit_cast(float, u);
}
__device__ __forceinline__ void gld16(const void* g, void* l) {
    __builtin_amdgcn_global_load_lds(
        (const __attribute__((address_space(1))) u32*)g,
        (__attribute__((address_space(3))) u32*)l, 16, 0, 0);
}

// DPP cross-lane (VALU pipe): rotate within 16-lane rows.
template<int CTRL>
__device__ __forceinline__ float dpp_rot(float x) {
    return __builtin_bit_cast(float,
        __builtin_amdgcn_update_dpp(0, __builtin_bit_cast(int, x),
                                    CTRL, 0xf, 0xf, true));
}
__device__ __forceinline__ float rowmax16(float x) {
    x = fmaxf(x, dpp_rot<0x121>(x));   // row_ror:1
    x = fmaxf(x, dpp_rot<0x122>(x));   // row_ror:2
    x = fmaxf(x, dpp_rot<0x124>(x));   // row_ror:4
    x = fmaxf(x, dpp_rot<0x128>(x));   // row_ror:8
    return x;
}
__device__ __forceinline__ float rowsum16(float x) {
    x += dpp_rot<0x121>(x);
    x += dpp_rot<0x122>(x);
    x += dpp_rot<0x124>(x);
    x += dpp_rot<0x128>(x);
    return x;
}

// ---------------- fused prep: x->bf16 convert + 4 weight transposes ----------------
// grid layout: [0,4096) cvt_x | [4096,8192) Wq | [8192,9216) Wk
//              [9216,10240) Wv | [10240,14336) Wo
__global__ __launch_bounds__(256) void prep_kernel(const float* __restrict__ x,
                                                   u16* __restrict__ xb,
                                                   const float* __restrict__ Wq,
                                                   const float* __restrict__ Wk,
                                                   const float* __restrict__ Wv,
                                                   const float* __restrict__ Wo,
                                                   u16* __restrict__ Wqkvt,
                                                   u16* __restrict__ Wot) {
    __shared__ float tile[32][33];
    const int bi = blockIdx.x;
    const int tid = threadIdx.x;
    if (bi < 4096) {
        size_t i = ((size_t)bi * 256 + tid) * 8;
        float4 a = *(const float4*)(x + i);
        float4 b = *(const float4*)(x + i + 4);
        uint4 v;
        v.x = (u32)f2bf(a.x) | ((u32)f2bf(a.y) << 16);
        v.y = (u32)f2bf(a.z) | ((u32)f2bf(a.w) << 16);
        v.z = (u32)f2bf(b.x) | ((u32)f2bf(b.y) << 16);
        v.w = (u32)f2bf(b.z) | ((u32)f2bf(b.w) << 16);
        *(uint4*)(xb + i) = v;
        return;
    }
    const float* src;
    u16* dst;
    int N, n0, k0;
    if (bi < 8192) {
        int t = bi - 4096; src = Wq; dst = Wqkvt; N = 2048;
        n0 = (t & 63) * 32; k0 = (t >> 6) * 32;
    } else if (bi < 9216) {
        int t = bi - 8192; src = Wk; dst = Wqkvt + (size_t)2048 * KDIM; N = 512;
        n0 = (t & 15) * 32; k0 = (t >> 4) * 32;
    } else if (bi < 10240) {
        int t = bi - 9216; src = Wv; dst = Wqkvt + (size_t)2560 * KDIM; N = 512;
        n0 = (t & 15) * 32; k0 = (t >> 4) * 32;
    } else {
        int t = bi - 10240; src = Wo; dst = Wot; N = 2048;
        n0 = (t & 63) * 32; k0 = (t >> 6) * 32;
    }
    const int tx = tid & 31, ty = tid >> 5;   // 32 x 8
#pragma unroll
    for (int r = 0; r < 4; r++)
        tile[ty + 8*r][tx] = src[(size_t)(k0 + ty + 8*r) * N + n0 + tx];
    __syncthreads();
#pragma unroll
    for (int r = 0; r < 4; r++)
        dst[(size_t)(n0 + ty + 8*r) * KDIM + k0 + tx] = f2bf(tile[tx][ty + 8*r]);
}

// ---------------- GEMM: C[m][n] = sum_k A[m][k] * Bt[n][k] ----------------
template<int OUT_BF16>
__global__ void __launch_bounds__(256, 2) gemm_bt(const u16* __restrict__ A,
                                                  const u16* __restrict__ Bt,
                                                  void* __restrict__ C, int ldc) {
    __shared__ __align__(16) u16 Al[128 * 32];
    __shared__ __align__(16) u16 Bl[128 * 32];
    const int tid = threadIdx.x;
    const int lane = tid & 63;
    const int w = tid >> 6;
    const int wm = (w & 1) * 64;
    const int wn = (w >> 1) * 64;
    const int quad = lane >> 4;
    const int l15 = lane & 15;
    const size_t bm = (size_t)blockIdx.x * 128;
    const size_t bn = (size_t)blockIdx.y * 128;

    const int srow = lane >> 2;
    const int kq = (lane & 3) ^ ((lane >> 3) & 3);
    const int i0 = 2 * w, i1 = 2 * w + 1;

    const u16* ga0 = A + (bm + i0*16 + srow) * KDIM + kq * 8;
    const u16* ga1 = A + (bm + i1*16 + srow) * KDIM + kq * 8;
    const u16* gb0 = Bt + (bn + i0*16 + srow) * KDIM + kq * 8;
    const u16* gb1 = Bt + (bn + i1*16 + srow) * KDIM + kq * 8;

    const int swz = ((quad ^ ((l15 >> 1) & 3)) << 3);
    int aoff[4], boff[4];
#pragma unroll
    for (int t = 0; t < 4; t++) {
        aoff[t] = (wm + t*16 + l15) * 32 + swz;
        boff[t] = (wn + t*16 + l15) * 32 + swz;
    }

    f32x4 acc[4][4] = {};

    for (int kt = 0; kt < KDIM / 32; kt++) {
        gld16(ga0 + kt*32, &Al[i0 * 512]);
        gld16(ga1 + kt*32, &Al[i1 * 512]);
        gld16(gb0 + kt*32, &Bl[i0 * 512]);
        gld16(gb1 + kt*32, &Bl[i1 * 512]);
        __syncthreads();
        bf16x8 af[4], bfv[4];
#pragma unroll
        for (int t = 0; t < 4; t++) {
            af[t]  = *(const bf16x8*)&Al[aoff[t]];
            bfv[t] = *(const bf16x8*)&Bl[boff[t]];
        }
#pragma unroll
        for (int mt = 0; mt < 4; mt++)
#pragma unroll
            for (int nt = 0; nt < 4; nt++)
                acc[mt][nt] = MFMA16(af[mt], bfv[nt], acc[mt][nt]);
        __syncthreads();
    }

#pragma unroll
    for (int mt = 0; mt < 4; mt++) {
        size_t m0 = bm + wm + mt*16 + quad*4;
#pragma unroll
        for (int nt = 0; nt < 4; nt++) {
            size_t n = bn + wn + nt*16 + l15;
#pragma unroll
            for (int r = 0; r < 4; r++) {
                if (OUT_BF16)
                    ((u16*)C)[(m0 + r) * (size_t)ldc + n] = f2bf(acc[mt][nt][r]);
                else
                    ((float*)C)[(m0 + r) * (size_t)ldc + n] = acc[mt][nt][r];
            }
        }
    }
}

// ---------------- rotary (in-place on Q and K parts of QKV), Q gets scale folded ----------------
__global__ __launch_bounds__(256) void rotary_kernel(u16* __restrict__ QKV,
                                                     const float* __restrict__ cosT,
                                                     const float* __restrict__ sinT) {
    int i = blockIdx.x * 256 + threadIdx.x;   // < 4096*320
    int m = i / 320;
    int rem = i - m * 320;
    int head = rem >> 4;
    int d0 = (rem & 15) << 2;                 // 0..60
    int t = m & (TDIM - 1);
    int col;
    float sc;
    if (head < NHEAD) {
        col = head * HD + d0;
        sc = 0.08838834764831845f * 1.4426950408889634f; // 1/sqrt(128) * log2(e)
    } else {
        col = HIDDIM + (head - NHEAD) * HD + d0;
        sc = 1.0f;
    }
    u16* p0 = QKV + (size_t)m * NQKV + col;
    u16* p1 = p0 + 64;
    float4 cv = *(const float4*)(cosT + t * HD + d0);
    float4 sv = *(const float4*)(sinT + t * HD + d0);
    uint2 qa = *(const uint2*)p0;
    uint2 qb = *(const uint2*)p1;
    float f0[4] = { bf2f(qa.x & 0xffffu), bf2f(qa.x >> 16), bf2f(qa.y & 0xffffu), bf2f(qa.y >> 16) };
    float f1[4] = { bf2f(qb.x & 0xffffu), bf2f(qb.x >> 16), bf2f(qb.y & 0xffffu), bf2f(qb.y >> 16) };
    float c[4] = { cv.x, cv.y, cv.z, cv.w };
    float s[4] = { sv.x, sv.y, sv.z, sv.w };
    u16 o0[4], o1[4];
#pragma unroll
    for (int k = 0; k < 4; k++) {
        o0[k] = f2bf((f0[k] * c[k] - f1[k] * s[k]) * sc);
        o1[k] = f2bf((f1[k] * c[k] + f0[k] * s[k]) * sc);
    }
    uint2 w0, w1;
    w0.x = (u32)o0[0] | ((u32)o0[1] << 16);
    w0.y = (u32)o0[2] | ((u32)o0[3] << 16);
    w1.x = (u32)o1[0] | ((u32)o1[1] << 16);
    w1.y = (u32)o1[2] | ((u32)o1[3] << 16);
    *(uint2*)p0 = w0;
    *(uint2*)p1 = w1;
}

// ---------------- flash attention, causal, GQA ----------------
// BQ=64, BKV=64, balanced pair (a, 31-a) -> 33 iters/block; grid 512 = 2/CU.
// 2 barriers/iter: K double-buffered (async gld16, prefetched 1 iter ahead),
// V prefetched to registers 1 iter ahead -> LV=72 padded Vt (write banks
// (4d+sp)%32 = exact 2-way = free; reads m97-style conflict-benign).
// Softmax reductions on the VALU pipe via DPP row_ror. P private (no barrier).
__global__ void __launch_bounds__(256, 2) attn_kernel(const u16* __restrict__ QKV,
                                                      u16* __restrict__ AO) {
    constexpr int LV = 72;   // Vt row stride
    constexpr int LP = 72;   // P row stride
    __shared__ __align__(16) u16 Kl[2][64 * 128];  // double-buffered K tile
    __shared__ __align__(16) u16 Vt[128 * LV];     // V transposed [d][s]
    __shared__ __align__(16) u16 Pl[64 * LP];      // P (per-wave private rows)

    const int pa = blockIdx.x;   // pair index 0..15
    const int h  = blockIdx.y;
    const int b  = blockIdx.z;
    const int kh = h >> 2;
    const int tid = threadIdx.x;
    const int lane = tid & 63;
    const int w = tid >> 6;
    const int quad = lane >> 4;
    const int l15 = lane & 15;

    const size_t rowbase = (size_t)b * TDIM;
    const u16* Qb = QKV + rowbase * NQKV + h * HD;
    const u16* Kb = QKV + rowbase * NQKV + HIDDIM + kh * HD;
    const u16* Vb = Kb + NKVH * HD;

    // K staging: instr i stages rows w*16+i*4..+3; chunk swizzle c ^= (row&7)
    int krow[4], kgch[4];
#pragma unroll
    for (int i = 0; i < 4; i++) {
        krow[i] = w*16 + i*4 + quad;
        kgch[i] = l15 ^ (krow[i] & 7);
    }
    // V staging lane mapping: sp (s-pair), dch (d-chunk of 8)
    const int sp0 = tid & 31, dch0 = tid >> 5, dch1 = dch0 + 8;

#pragma unroll 1
    for (int ph = 0; ph < 2; ph++) {
        const int qt = ph ? (31 - pa) : pa;   // Q-tile index, 64 rows

        // Q fragments: wave w owns rows qt*64 + w*16 .. +15
        bf16x8 qf[4];
        {
            const u16* qr = Qb + (size_t)(qt*64 + w*16 + l15) * NQKV;
#pragma unroll
            for (int kt = 0; kt < 4; kt++)
                qf[kt] = *(const bf16x8*)(qr + kt*32 + quad*8);
        }
        f32x4 O[8] = {};
        float mrun[4], lrun[4];
#pragma unroll
        for (int r = 0; r < 4; r++) { mrun[r] = -1e30f; lrun[r] = 0.0f; }

        // ---- prologue: prefetch K(0) -> Kl[0], V(0) -> regs ----
#pragma unroll
        for (int i = 0; i < 4; i++)
            gld16(Kb + (size_t)krow[i] * NQKV + kgch[i]*8, &Kl[0][(w*16 + i*4) * 128]);
        uint4 vr0a, vr0b, vr1a, vr1b;
        {
            const u16* g0 = Vb + (size_t)(sp0*2) * NQKV + dch0*8;
            vr0a = *(const uint4*)g0;
            vr0b = *(const uint4*)(g0 + NQKV);
            const u16* g1 = Vb + (size_t)(sp0*2) * NQKV + dch1*8;
            vr1a = *(const uint4*)g1;
            vr1b = *(const uint4*)(g1 + NQKV);
        }

#pragma unroll 1
        for (int j = 0; j <= qt; j++) {
            // ---- write V(j) regs -> Vt (LV=72: 2-way banks, free) ----
            {
                u32 ra[4] = { vr0a.x, vr0a.y, vr0a.z, vr0a.w };
                u32 rb[4] = { vr0b.x, vr0b.y, vr0b.z, vr0b.w };
                int s = sp0*2, d0 = dch0*8;
#pragma unroll
                for (int k2 = 0; k2 < 4; k2++) {
                    u32 lo = (ra[k2] & 0xffffu) | (rb[k2] << 16);
                    u32 hi = (ra[k2] >> 16) | (rb[k2] & 0xffff0000u);
                    *(u32*)&Vt[(d0 + 2*k2)     * LV + s] = lo;
                    *(u32*)&Vt[(d0 + 2*k2 + 1) * LV + s] = hi;
                }
                u32 rc[4] = { vr1a.x, vr1a.y, vr1a.z, vr1a.w };
                u32 rd[4] = { vr1b.x, vr1b.y, vr1b.z, vr1b.w };
                d0 = dch1*8;
#pragma unroll
                for (int k2 = 0; k2 < 4; k2++) {
                    u32 lo = (rc[k2] & 0xffffu) | (rd[k2] << 16);
                    u32 hi = (rc[k2] >> 16) | (rd[k2] & 0xffff0000u);
                    *(u32*)&Vt[(d0 + 2*k2)     * LV + s] = lo;
                    *(u32*)&Vt[(d0 + 2*k2 + 1) * LV + s] = hi;
                }
            }
            __syncthreads();   // [A] K(j) landed (vmcnt drain), Vt visible

            // ---- prefetch K(j+1), V(j+1) (hidden behind this iter's compute) ----
            if (j < qt) {
                const u16* Kbn = Kb + (size_t)(j+1) * 64 * NQKV;
                u16* kl = Kl[(j+1) & 1];
#pragma unroll
                for (int i = 0; i < 4; i++)
                    gld16(Kbn + (size_t)krow[i] * NQKV + kgch[i]*8, &kl[(w*16 + i*4) * 128]);
                const u16* Vbn = Vb + (size_t)(j+1) * 64 * NQKV;
                const u16* g0 = Vbn + (size_t)(sp0*2) * NQKV + dch0*8;
                vr0a = *(const uint4*)g0;
                vr0b = *(const uint4*)(g0 + NQKV);
                const u16* g1 = Vbn + (size_t)(sp0*2) * NQKV + dch1*8;
                vr1a = *(const uint4*)g1;
                vr1b = *(const uint4*)(g1 + NQKV);
            }

            // ---- S = Q K^T (Q pre-scaled by 1/sqrt(d)*log2e) ----
            const u16* kl = Kl[j & 1];
            f32x4 S[4] = {};
#pragma unroll
            for (int kt = 0; kt < 4; kt++) {
                int p = (kt*4 + quad) ^ (l15 & 7);
#pragma unroll
                for (int nt = 0; nt < 4; nt++) {
                    bf16x8 bfr = *(const bf16x8*)&kl[(nt*16 + l15)*128 + p*8];
                    S[nt] = MFMA16(qf[kt], bfr, S[nt]);
                }
            }

            // ---- causal mask: only the diagonal tile is boundary ----
            if (j == qt) {
                int toff = w*16 + quad*4;
#pragma unroll
                for (int nt = 0; nt < 4; nt++) {
                    int scol = nt*16 + l15;
#pragma unroll
                    for (int r = 0; r < 4; r++)
                        if (scol > toff + r) S[nt][r] = -1e30f;
                }
            }

            // ---- online softmax (row = quad*4+r; DPP reductions, VALU pipe) ----
            float alpha[4];
#pragma unroll
            for (int r = 0; r < 4; r++) {
                float mx = fmaxf(fmaxf(S[0][r], S[1][r]), fmaxf(S[2][r], S[3][r]));
                mx = rowmax16(mx);
                float mnew = fmaxf(mrun[r], mx);
                float al = __builtin_amdgcn_exp2f(mrun[r] - mnew);
                mrun[r] = mnew;
                alpha[r] = al;
                float rs = 0.0f;
#pragma unroll
                for (int nt = 0; nt < 4; nt++) {
                    float p = __builtin_amdgcn_exp2f(S[nt][r] - mnew);
                    S[nt][r] = p;
                    rs += p;
                }
                rs = rowsum16(rs);
                lrun[r] = lrun[r] * al + rs;
            }
            bool need = (alpha[0] < 1.0f) | (alpha[1] < 1.0f) |
                        (alpha[2] < 1.0f) | (alpha[3] < 1.0f);
            if (__any(need)) {
#pragma unroll
                for (int nt = 0; nt < 8; nt++)
#pragma unroll
                    for (int r = 0; r < 4; r++)
                        O[nt][r] *= alpha[r];
            }

            // ---- write P into private region (own wave's rows; no barrier) ----
#pragma unroll
            for (int nt = 0; nt < 4; nt++)
#pragma unroll
                for (int r = 0; r < 4; r++)
                    Pl[(w*16 + quad*4 + r) * LP + nt*16 + l15] = f2bf(S[nt][r]);

            // ---- O += P V ----
#pragma unroll
            for (int kt = 0; kt < 2; kt++) {
                bf16x8 pa_f = *(const bf16x8*)&Pl[(w*16 + l15) * LP + kt*32 + quad*8];
#pragma unroll
                for (int nt = 0; nt < 8; nt++) {
                    bf16x8 bv = *(const bf16x8*)&Vt[(nt*16 + l15) * LV + kt*32 + quad*8];
                    O[nt] = MFMA16(pa_f, bv, O[nt]);
                }
            }
            __syncthreads();   // [B] Vt / K[j&1] free for next iter's staging
        }

        // ---- epilogue: O /= l, store bf16 ----
        float inv[4];
#pragma unroll
        for (int r = 0; r < 4; r++) inv[r] = 1.0f / lrun[r];
        size_t row0 = rowbase + qt*64 + w*16 + quad*4;
#pragma unroll
        for (int nt = 0; nt < 8; nt++) {
            size_t cix = (size_t)h * HD + nt*16 + l15;
#pragma unroll
            for (int r = 0; r < 4; r++)
                AO[(row0 + r) * HIDDIM + cix] = f2bf(O[nt][r] * inv[r]);
        }
    }
}

extern "C" void kernel_launch(void* const* d_in, const int* in_sizes, int n_in,
                              void* d_out, int out_size, void* d_ws, size_t ws_size,
                              hipStream_t stream) {
    (void)in_sizes; (void)n_in; (void)out_size; (void)ws_size;
    const float* x    = (const float*)d_in[0];
    const float* cosT = (const float*)d_in[1];
    const float* sinT = (const float*)d_in[2];
    const float* Wq   = (const float*)d_in[3];
    const float* Wk   = (const float*)d_in[4];
    const float* Wv   = (const float*)d_in[5];
    const float* Wo   = (const float*)d_in[6];

    char* ws = (char*)d_ws;
    u16* QKV   = (u16*)ws;                                             // 4096*3072 bf16
    u16* xb    = (u16*)(ws + (size_t)MROWS * NQKV * 2);                // 4096*2048 (then attn_out)
    u16* Wqkvt = (u16*)(ws + (size_t)MROWS * NQKV * 2 + (size_t)MROWS * HIDDIM * 2); // 3072*2048
    u16* Wot   = Wqkvt + (size_t)NQKV * KDIM;                          // 2048*2048

    prep_kernel<<<14336, 256, 0, stream>>>(x, xb, Wq, Wk, Wv, Wo, Wqkvt, Wot);
    gemm_bt<1><<<dim3(32, 24), 256, 0, stream>>>(xb, Wqkvt, QKV, NQKV);
    rotary_kernel<<<5120, 256, 0, stream>>>(QKV, cosT, sinT);
    attn_kernel<<<dim3(16, 16, 2), 256, 0, stream>>>(QKV, xb);
    gemm_bt<0><<<dim3(32, 16), 256, 0, stream>>>(xb, Wot, d_out, HIDDIM);
}